// Round 6
// baseline (664.130 us; speedup 1.0000x reference)
//
#include <hip/hip_runtime.h>

// SIREN fused MLP, v6 = v4 (best passing) with ONE change:
// __launch_bounds__(512,4) -> 2 independent 8-wave blocks per CU.
// Independent blocks share no barriers, so block A's sin-epilogue (VALU)
// overlaps block B's MFMA phase (m114 co-scheduling) — the desync that
// within-wave interleaving (r4 JIT, r5 SGB) could not provide.
#define NPTS 262144
#define HID  128
#define NB   7
#define NMAT 14

typedef __attribute__((ext_vector_type(8))) short bf16x8;
typedef __attribute__((ext_vector_type(4))) float f32x4;
typedef __attribute__((ext_vector_type(4))) unsigned int u32x4;

constexpr float OMEGA  = 30.0f;
constexpr float INV2PI = 0.15915494309189535f;

#define WIMG_BYTES (NMAT*32768)   // 458752
#define BIAS_ELEMS (NMAT*128)     // 1792 f32, prescaled
__device__ __align__(16) unsigned char g_img[WIMG_BYTES + BIAS_ELEMS*4];

__device__ __forceinline__ unsigned short f2bf(float v) {
    unsigned int u = __float_as_uint(v);
    u += 0x7fffu + ((u >> 16) & 1u);          // RNE
    return (unsigned short)(u >> 16);
}

__device__ __forceinline__ float sin_rev(float r) {
    // sin(2*pi*r): v_fract (exact periodic reduce) + v_sin (revolutions)
    return __builtin_amdgcn_sinf(__builtin_amdgcn_fractf(r));
}

__device__ __forceinline__ unsigned int cvtpk(float lo, float hi) {
    unsigned int r;
    asm("v_cvt_pk_bf16_f32 %0, %1, %2" : "=v"(r) : "v"(lo), "v"(hi));
    return r;
}

// ---- prep: bake scaled/permuted/swizzled bf16 weight image + biases ----
__global__ void prep(const float* __restrict__ Wa, const float* __restrict__ ba,
                     const float* __restrict__ Wb, const float* __restrict__ bb) {
    int idx = blockIdx.x * 256 + threadIdx.x;
    const float bscale = OMEGA * INV2PI;
    const int total = NMAT * HID * HID;
    if (idx < total) {
        int mi = idx >> 14, rc = idx & 16383;
        int row = rc >> 7, col = rc & 127;
        int l = mi >> 1;
        float sc = bscale, v;
        if (mi & 1) v = Wb[l*16384 + rc];
        else { v = Wa[l*16384 + rc]; if (l > 0) sc *= 0.5f; }   // w1=0.5, blk>0
        int t = col >> 4, g = (col >> 2) & 3, r = col & 3;
        int kp = ((t >> 1) << 5) | (g << 3) | ((t & 1) << 2) | r;
        int byte = mi*32768 + row*256 + ((kp*2) ^ ((row & 7) << 4));
        *(unsigned short*)(g_img + byte) = f2bf(v * sc);
    } else if (idx < total + BIAS_ELEMS) {
        int e = idx - total;
        int j = e >> 7, f = e & 127, l = j >> 1;
        float v = (j & 1) ? bb[l*HID + f] : ba[l*HID + f];
        ((float*)(g_img + WIMG_BYTES))[e] = v * bscale;
    }
}

// ---- main: 8 waves x 32 pts = 256 pts/block; LDS = Wdbuf(64K)+bias(7K) ----
#define LDS_BYTES 72704

__launch_bounds__(512, 4)
__global__ void siren_mlp(const float* __restrict__ x,
                          const float* __restrict__ W0,
                          const float* __restrict__ b0,
                          const float* __restrict__ Wf,
                          const float* __restrict__ bfin,
                          float* __restrict__ out) {
    extern __shared__ char smem[];          // buf0 @0, buf1 @32768, bsc @65536
    float* bsc = (float*)(smem + 65536);

    const int tid  = threadIdx.x;
    const int lane = tid & 63;
    const int w    = tid >> 6;
    const int l16  = lane & 15;
    const int g    = lane >> 4;
    const int swz  = (l16 & 7) << 4;
    const int ptb  = blockIdx.x * 256 + w * 32;
    const float bscale = OMEGA * INV2PI;

    // ---- prologue: issue Wa[0] + biases ----
    u32x4 st[4];
    {
        const u32x4* gp = (const u32x4*)(g_img);
        #pragma unroll
        for (int i = 0; i < 4; ++i) st[i] = gp[w*256 + i*64 + lane];
    }
    u32x4 bld;
    if (tid < 448) bld = ((const u32x4*)(g_img + WIMG_BYTES))[tid];

    // ---- first layer: h = sin(omega*(x@W0^T+b0)), f32 VALU, acc-order ----
    f32x4 resid[2][8];
    #pragma unroll
    for (int s = 0; s < 2; ++s) {
        int pt = ptb + 16*s + l16;
        float x0 = x[3*pt], x1 = x[3*pt+1], x2 = x[3*pt+2];
        #pragma unroll
        for (int t = 0; t < 8; ++t)
            #pragma unroll
            for (int r = 0; r < 4; ++r) {
                int f = 16*t + 4*g + r;
                float arg = (x0*W0[3*f] + x1*W0[3*f+1] + x2*W0[3*f+2] + b0[f]) * bscale;
                resid[s][t][r] = sin_rev(arg);
            }
    }
    {
        u32x4* lp = (u32x4*)smem;
        #pragma unroll
        for (int i = 0; i < 4; ++i) lp[w*256 + i*64 + lane] = st[i];
        if (tid < 448) ((u32x4*)bsc)[tid] = bld;
    }
    __syncthreads();

    f32x4 acc1[2][8], acc2[2][8];
    // acc2 = 0 so blk-0's JIT residual update adds sin(0) == 0 (branch-free)
    #pragma unroll
    for (int s = 0; s < 2; ++s)
        #pragma unroll
        for (int t = 0; t < 8; ++t) acc2[s][t] = (f32x4){0.f, 0.f, 0.f, 0.f};

    for (int blk = 0; blk < NB; ++blk) {
        // issue Wb[blk] loads (in flight during matmul1)
        {
            const u32x4* gq = (const u32x4*)(g_img + (2*blk+1)*32768);
            #pragma unroll
            for (int i = 0; i < 4; ++i) st[i] = gq[w*256 + i*64 + lane];
        }

        // ---- matmul1: acc1 = b' + Wa'·h  (A from buf0), JIT pack ----
        {
            const float* bj = bsc + (2*blk)*128;
            #pragma unroll
            for (int t = 0; t < 8; ++t) {
                f32x4 bv = *(const f32x4*)(bj + 16*t + 4*g);
                acc1[0][t] = bv; acc1[1][t] = bv;
            }
            const char* wb = smem;
            #pragma unroll
            for (int ks = 0; ks < 4; ++ks) {
                unsigned int pk[2][4];
                // JIT: finish prev matmul2 epilogue for t=2ks,2ks+1, then pack
                #pragma unroll
                for (int s = 0; s < 2; ++s)
                    #pragma unroll
                    for (int tt = 0; tt < 2; ++tt) {
                        int t = 2*ks + tt;
                        #pragma unroll
                        for (int r = 0; r < 4; ++r)
                            resid[s][t][r] += sin_rev(acc2[s][t][r]);
                        pk[s][tt*2]   = cvtpk(resid[s][t][0], resid[s][t][1]);
                        pk[s][tt*2+1] = cvtpk(resid[s][t][2], resid[s][t][3]);
                    }
                u32x4 u0 = {pk[0][0], pk[0][1], pk[0][2], pk[0][3]};
                u32x4 u1 = {pk[1][0], pk[1][1], pk[1][2], pk[1][3]};
                bf16x8 bf0 = __builtin_bit_cast(bf16x8, u0);
                bf16x8 bf1 = __builtin_bit_cast(bf16x8, u1);
                #pragma unroll
                for (int t = 0; t < 8; ++t) {
                    bf16x8 a = *(const bf16x8*)(wb + (16*t + l16)*256 + ((64*ks + 16*g) ^ swz));
                    acc1[0][t] = __builtin_amdgcn_mfma_f32_16x16x32_bf16(a, bf0, acc1[0][t], 0,0,0);
                    acc1[1][t] = __builtin_amdgcn_mfma_f32_16x16x32_bf16(a, bf1, acc1[1][t], 0,0,0);
                }
            }
        }
        // write Wb[blk] -> buf1 BEFORE the barrier
        {
            u32x4* lq = (u32x4*)(smem + 32768);
            #pragma unroll
            for (int i = 0; i < 4; ++i) lq[w*256 + i*64 + lane] = st[i];
        }
        __syncthreads();
        // issue Wa[blk+1] loads (in flight during matmul2)
        if (blk < NB-1) {
            const u32x4* gp = (const u32x4*)(g_img + (2*blk+2)*32768);
            #pragma unroll
            for (int i = 0; i < 4; ++i) st[i] = gp[w*256 + i*64 + lane];
        }

        // ---- matmul2: acc2 = b' + Wb'·sin(acc1)  (A from buf1), JIT pack ----
        {
            const float* bj = bsc + (2*blk+1)*128;
            #pragma unroll
            for (int t = 0; t < 8; ++t) {
                f32x4 bv = *(const f32x4*)(bj + 16*t + 4*g);
                acc2[0][t] = bv; acc2[1][t] = bv;
            }
            const char* wb = smem + 32768;
            #pragma unroll
            for (int ks = 0; ks < 4; ++ks) {
                unsigned int pk[2][4];
                #pragma unroll
                for (int s = 0; s < 2; ++s)
                    #pragma unroll
                    for (int tt = 0; tt < 2; ++tt) {
                        int t = 2*ks + tt;
                        float v0 = sin_rev(acc1[s][t][0]);
                        float v1 = sin_rev(acc1[s][t][1]);
                        float v2 = sin_rev(acc1[s][t][2]);
                        float v3 = sin_rev(acc1[s][t][3]);
                        pk[s][tt*2]   = cvtpk(v0, v1);
                        pk[s][tt*2+1] = cvtpk(v2, v3);
                    }
                u32x4 u0 = {pk[0][0], pk[0][1], pk[0][2], pk[0][3]};
                u32x4 u1 = {pk[1][0], pk[1][1], pk[1][2], pk[1][3]};
                bf16x8 bf0 = __builtin_bit_cast(bf16x8, u0);
                bf16x8 bf1 = __builtin_bit_cast(bf16x8, u1);
                #pragma unroll
                for (int t = 0; t < 8; ++t) {
                    bf16x8 a = *(const bf16x8*)(wb + (16*t + l16)*256 + ((64*ks + 16*g) ^ swz));
                    acc2[0][t] = __builtin_amdgcn_mfma_f32_16x16x32_bf16(a, bf0, acc2[0][t], 0,0,0);
                    acc2[1][t] = __builtin_amdgcn_mfma_f32_16x16x32_bf16(a, bf1, acc2[1][t], 0,0,0);
                }
            }
        }
        // write Wa[blk+1] -> buf0 BEFORE the end barrier
        if (blk < NB-1) {
            u32x4* lp = (u32x4*)smem;
            #pragma unroll
            for (int i = 0; i < 4; ++i) lp[w*256 + i*64 + lane] = st[i];
        }
        __syncthreads();
    }

    // ---- tail: last residual update (w2=0.5) + final linear ----
    #pragma unroll
    for (int s = 0; s < 2; ++s) {
        float part = 0.f;
        #pragma unroll
        for (int t = 0; t < 8; ++t) {
            f32x4 wv = *(const f32x4*)(Wf + 16*t + 4*g);
            #pragma unroll
            for (int r = 0; r < 4; ++r) {
                float hn = 0.5f * (resid[s][t][r] + sin_rev(acc2[s][t][r]));
                part += hn * wv[r];
            }
        }
        part += __shfl_xor(part, 16);
        part += __shfl_xor(part, 32);
        if (g == 0) out[ptb + 16*s + l16] = part + bfin[0];
    }
}

extern "C" void kernel_launch(void* const* d_in, const int* in_sizes, int n_in,
                              void* d_out, int out_size, void* d_ws, size_t ws_size,
                              hipStream_t stream) {
    const float* x   = (const float*)d_in[0];
    const float* W0  = (const float*)d_in[1];
    const float* b0  = (const float*)d_in[2];
    const float* Wa  = (const float*)d_in[3];
    const float* ba  = (const float*)d_in[4];
    const float* Wb  = (const float*)d_in[5];
    const float* bb  = (const float*)d_in[6];
    const float* Wf  = (const float*)d_in[7];
    const float* bf_ = (const float*)d_in[8];

    prep<<<dim3(903), dim3(256), 0, stream>>>(Wa, ba, Wb, bb);
    hipFuncSetAttribute(reinterpret_cast<const void*>(siren_mlp),
                        hipFuncAttributeMaxDynamicSharedMemorySize, LDS_BYTES);
    siren_mlp<<<dim3(NPTS/256), dim3(512), LDS_BYTES, stream>>>(
        x, W0, b0, Wf, bf_, (float*)d_out);
}

// Round 9
// 149.263 us; speedup vs baseline: 4.4494x; 4.4494x over previous
//
#include <hip/hip_runtime.h>

// SIREN fused MLP, v9 = v4 (best passing, 148.8us) with ONE change:
// __launch_bounds__(512, 2). Empirically on this toolchain (v6: (512,4) ->
// VGPR cap 64 = 2048/32 waves), the 2nd arg scales as blocks/CU for 8-wave
// blocks; (512,2) -> 16 waves/CU -> VGPR cap 128 >= our 116 -> no spill,
// TWO independent 8-wave blocks per CU (LDS 2x72704 <= 160K). Independent
// blocks share no barriers -> block A's sin-epilogue (VALU) overlaps block
// B's MFMA phase (m114) without any schedule-fragile code motion.
// fract is REQUIRED before v_sin (v8 failure: HW sin doesn't range-reduce
// accurately; ISA doc says reduce with v_fract first).
#define NPTS 262144
#define HID  128
#define NB   7
#define NMAT 14

typedef __attribute__((ext_vector_type(8))) short bf16x8;
typedef __attribute__((ext_vector_type(4))) float f32x4;
typedef __attribute__((ext_vector_type(4))) unsigned int u32x4;

constexpr float OMEGA  = 30.0f;
constexpr float INV2PI = 0.15915494309189535f;

#define WIMG_BYTES (NMAT*32768)   // 458752
#define BIAS_ELEMS (NMAT*128)     // 1792 f32, prescaled
__device__ __align__(16) unsigned char g_img[WIMG_BYTES + BIAS_ELEMS*4];

__device__ __forceinline__ unsigned short f2bf(float v) {
    unsigned int u = __float_as_uint(v);
    u += 0x7fffu + ((u >> 16) & 1u);          // RNE
    return (unsigned short)(u >> 16);
}

__device__ __forceinline__ float sin_rev(float r) {
    // sin(2*pi*r): v_fract (exact periodic reduce, REQUIRED) + v_sin
    return __builtin_amdgcn_sinf(__builtin_amdgcn_fractf(r));
}

__device__ __forceinline__ unsigned int cvtpk(float lo, float hi) {
    unsigned int r;
    asm("v_cvt_pk_bf16_f32 %0, %1, %2" : "=v"(r) : "v"(lo), "v"(hi));
    return r;
}

// ---- prep: bake scaled/permuted/swizzled bf16 weight image + biases ----
__global__ void prep(const float* __restrict__ Wa, const float* __restrict__ ba,
                     const float* __restrict__ Wb, const float* __restrict__ bb) {
    int idx = blockIdx.x * 256 + threadIdx.x;
    const float bscale = OMEGA * INV2PI;
    const int total = NMAT * HID * HID;
    if (idx < total) {
        int mi = idx >> 14, rc = idx & 16383;
        int row = rc >> 7, col = rc & 127;
        int l = mi >> 1;
        float sc = bscale, v;
        if (mi & 1) v = Wb[l*16384 + rc];
        else { v = Wa[l*16384 + rc]; if (l > 0) sc *= 0.5f; }   // w1=0.5, blk>0
        int t = col >> 4, g = (col >> 2) & 3, r = col & 3;
        int kp = ((t >> 1) << 5) | (g << 3) | ((t & 1) << 2) | r;
        int byte = mi*32768 + row*256 + ((kp*2) ^ ((row & 7) << 4));
        *(unsigned short*)(g_img + byte) = f2bf(v * sc);
    } else if (idx < total + BIAS_ELEMS) {
        int e = idx - total;
        int j = e >> 7, f = e & 127, l = j >> 1;
        float v = (j & 1) ? bb[l*HID + f] : ba[l*HID + f];
        ((float*)(g_img + WIMG_BYTES))[e] = v * bscale;
    }
}

// ---- main: 8 waves x 32 pts = 256 pts/block; LDS = Wdbuf(64K)+bias(7K) ----
#define LDS_BYTES 72704

__launch_bounds__(512, 2)
__global__ void siren_mlp(const float* __restrict__ x,
                          const float* __restrict__ W0,
                          const float* __restrict__ b0,
                          const float* __restrict__ Wf,
                          const float* __restrict__ bfin,
                          float* __restrict__ out) {
    extern __shared__ char smem[];          // buf0 @0, buf1 @32768, bsc @65536
    float* bsc = (float*)(smem + 65536);

    const int tid  = threadIdx.x;
    const int lane = tid & 63;
    const int w    = tid >> 6;
    const int l16  = lane & 15;
    const int g    = lane >> 4;
    const int swz  = (l16 & 7) << 4;
    const int ptb  = blockIdx.x * 256 + w * 32;
    const float bscale = OMEGA * INV2PI;

    // ---- prologue: issue Wa[0] + biases ----
    u32x4 st[4];
    {
        const u32x4* gp = (const u32x4*)(g_img);
        #pragma unroll
        for (int i = 0; i < 4; ++i) st[i] = gp[w*256 + i*64 + lane];
    }
    u32x4 bld;
    if (tid < 448) bld = ((const u32x4*)(g_img + WIMG_BYTES))[tid];

    // ---- first layer: h = sin(omega*(x@W0^T+b0)), f32 VALU, acc-order ----
    f32x4 resid[2][8];
    #pragma unroll
    for (int s = 0; s < 2; ++s) {
        int pt = ptb + 16*s + l16;
        float x0 = x[3*pt], x1 = x[3*pt+1], x2 = x[3*pt+2];
        #pragma unroll
        for (int t = 0; t < 8; ++t)
            #pragma unroll
            for (int r = 0; r < 4; ++r) {
                int f = 16*t + 4*g + r;
                float arg = (x0*W0[3*f] + x1*W0[3*f+1] + x2*W0[3*f+2] + b0[f]) * bscale;
                resid[s][t][r] = sin_rev(arg);
            }
    }
    {
        u32x4* lp = (u32x4*)smem;
        #pragma unroll
        for (int i = 0; i < 4; ++i) lp[w*256 + i*64 + lane] = st[i];
        if (tid < 448) ((u32x4*)bsc)[tid] = bld;
    }
    __syncthreads();

    f32x4 acc1[2][8], acc2[2][8];
    // acc2 = 0 so blk-0's JIT residual update adds sin(0) == 0 (branch-free)
    #pragma unroll
    for (int s = 0; s < 2; ++s)
        #pragma unroll
        for (int t = 0; t < 8; ++t) acc2[s][t] = (f32x4){0.f, 0.f, 0.f, 0.f};

    for (int blk = 0; blk < NB; ++blk) {
        // issue Wb[blk] loads (in flight during matmul1)
        {
            const u32x4* gq = (const u32x4*)(g_img + (2*blk+1)*32768);
            #pragma unroll
            for (int i = 0; i < 4; ++i) st[i] = gq[w*256 + i*64 + lane];
        }

        // ---- matmul1: acc1 = b' + Wa'·h  (A from buf0), JIT pack ----
        {
            const float* bj = bsc + (2*blk)*128;
            #pragma unroll
            for (int t = 0; t < 8; ++t) {
                f32x4 bv = *(const f32x4*)(bj + 16*t + 4*g);
                acc1[0][t] = bv; acc1[1][t] = bv;
            }
            const char* wb = smem;
            #pragma unroll
            for (int ks = 0; ks < 4; ++ks) {
                unsigned int pk[2][4];
                // JIT: finish prev matmul2 epilogue for t=2ks,2ks+1, then pack
                #pragma unroll
                for (int s = 0; s < 2; ++s)
                    #pragma unroll
                    for (int tt = 0; tt < 2; ++tt) {
                        int t = 2*ks + tt;
                        #pragma unroll
                        for (int r = 0; r < 4; ++r)
                            resid[s][t][r] += sin_rev(acc2[s][t][r]);
                        pk[s][tt*2]   = cvtpk(resid[s][t][0], resid[s][t][1]);
                        pk[s][tt*2+1] = cvtpk(resid[s][t][2], resid[s][t][3]);
                    }
                u32x4 u0 = {pk[0][0], pk[0][1], pk[0][2], pk[0][3]};
                u32x4 u1 = {pk[1][0], pk[1][1], pk[1][2], pk[1][3]};
                bf16x8 bf0 = __builtin_bit_cast(bf16x8, u0);
                bf16x8 bf1 = __builtin_bit_cast(bf16x8, u1);
                #pragma unroll
                for (int t = 0; t < 8; ++t) {
                    bf16x8 a = *(const bf16x8*)(wb + (16*t + l16)*256 + ((64*ks + 16*g) ^ swz));
                    acc1[0][t] = __builtin_amdgcn_mfma_f32_16x16x32_bf16(a, bf0, acc1[0][t], 0,0,0);
                    acc1[1][t] = __builtin_amdgcn_mfma_f32_16x16x32_bf16(a, bf1, acc1[1][t], 0,0,0);
                }
            }
        }
        // write Wb[blk] -> buf1 BEFORE the barrier
        {
            u32x4* lq = (u32x4*)(smem + 32768);
            #pragma unroll
            for (int i = 0; i < 4; ++i) lq[w*256 + i*64 + lane] = st[i];
        }
        __syncthreads();
        // issue Wa[blk+1] loads (in flight during matmul2)
        if (blk < NB-1) {
            const u32x4* gp = (const u32x4*)(g_img + (2*blk+2)*32768);
            #pragma unroll
            for (int i = 0; i < 4; ++i) st[i] = gp[w*256 + i*64 + lane];
        }

        // ---- matmul2: acc2 = b' + Wb'·sin(acc1)  (A from buf1), JIT pack ----
        {
            const float* bj = bsc + (2*blk+1)*128;
            #pragma unroll
            for (int t = 0; t < 8; ++t) {
                f32x4 bv = *(const f32x4*)(bj + 16*t + 4*g);
                acc2[0][t] = bv; acc2[1][t] = bv;
            }
            const char* wb = smem + 32768;
            #pragma unroll
            for (int ks = 0; ks < 4; ++ks) {
                unsigned int pk[2][4];
                #pragma unroll
                for (int s = 0; s < 2; ++s)
                    #pragma unroll
                    for (int tt = 0; tt < 2; ++tt) {
                        int t = 2*ks + tt;
                        float v0 = sin_rev(acc1[s][t][0]);
                        float v1 = sin_rev(acc1[s][t][1]);
                        float v2 = sin_rev(acc1[s][t][2]);
                        float v3 = sin_rev(acc1[s][t][3]);
                        pk[s][tt*2]   = cvtpk(v0, v1);
                        pk[s][tt*2+1] = cvtpk(v2, v3);
                    }
                u32x4 u0 = {pk[0][0], pk[0][1], pk[0][2], pk[0][3]};
                u32x4 u1 = {pk[1][0], pk[1][1], pk[1][2], pk[1][3]};
                bf16x8 bf0 = __builtin_bit_cast(bf16x8, u0);
                bf16x8 bf1 = __builtin_bit_cast(bf16x8, u1);
                #pragma unroll
                for (int t = 0; t < 8; ++t) {
                    bf16x8 a = *(const bf16x8*)(wb + (16*t + l16)*256 + ((64*ks + 16*g) ^ swz));
                    acc2[0][t] = __builtin_amdgcn_mfma_f32_16x16x32_bf16(a, bf0, acc2[0][t], 0,0,0);
                    acc2[1][t] = __builtin_amdgcn_mfma_f32_16x16x32_bf16(a, bf1, acc2[1][t], 0,0,0);
                }
            }
        }
        // write Wa[blk+1] -> buf0 BEFORE the end barrier
        if (blk < NB-1) {
            u32x4* lp = (u32x4*)smem;
            #pragma unroll
            for (int i = 0; i < 4; ++i) lp[w*256 + i*64 + lane] = st[i];
        }
        __syncthreads();
    }

    // ---- tail: last residual update (w2=0.5) + final linear ----
    #pragma unroll
    for (int s = 0; s < 2; ++s) {
        float part = 0.f;
        #pragma unroll
        for (int t = 0; t < 8; ++t) {
            f32x4 wv = *(const f32x4*)(Wf + 16*t + 4*g);
            #pragma unroll
            for (int r = 0; r < 4; ++r) {
                float hn = 0.5f * (resid[s][t][r] + sin_rev(acc2[s][t][r]));
                part += hn * wv[r];
            }
        }
        part += __shfl_xor(part, 16);
        part += __shfl_xor(part, 32);
        if (g == 0) out[ptb + 16*s + l16] = part + bfin[0];
    }
}

extern "C" void kernel_launch(void* const* d_in, const int* in_sizes, int n_in,
                              void* d_out, int out_size, void* d_ws, size_t ws_size,
                              hipStream_t stream) {
    const float* x   = (const float*)d_in[0];
    const float* W0  = (const float*)d_in[1];
    const float* b0  = (const float*)d_in[2];
    const float* Wa  = (const float*)d_in[3];
    const float* ba  = (const float*)d_in[4];
    const float* Wb  = (const float*)d_in[5];
    const float* bb  = (const float*)d_in[6];
    const float* Wf  = (const float*)d_in[7];
    const float* bf_ = (const float*)d_in[8];

    prep<<<dim3(903), dim3(256), 0, stream>>>(Wa, ba, Wb, bb);
    hipFuncSetAttribute(reinterpret_cast<const void*>(siren_mlp),
                        hipFuncAttributeMaxDynamicSharedMemorySize, LDS_BYTES);
    siren_mlp<<<dim3(NPTS/256), dim3(512), LDS_BYTES, stream>>>(
        x, W0, b0, Wf, bf_, (float*)d_out);
}